// Round 21
// baseline (107.657 us; speedup 1.0000x reference)
//
#include <hip/hip_runtime.h>
#include <hip/hip_bf16.h>

typedef __attribute__((ext_vector_type(8))) short bf16x8;
typedef __attribute__((ext_vector_type(4))) float f32x4;
typedef unsigned short u16;
typedef unsigned int u32;

#define MFMA16(a, b, c) __builtin_amdgcn_mfma_f32_16x16x32_bf16((a), (b), (c), 0, 0, 0)

__device__ __forceinline__ void gld16(const void* g, void* l) {
  __builtin_amdgcn_global_load_lds((const __attribute__((address_space(1))) u32*)g,
                                   (__attribute__((address_space(3))) u32*)l, 16, 0, 0);
}

__device__ __forceinline__ u16 f2bf(float f) {
  u32 x = __float_as_uint(f);
  x += 0x7fffu + ((x >> 16) & 1u);
  return (u16)(x >> 16);
}
__device__ __forceinline__ u32 pk2(float lo, float hi) {
  return (u32)f2bf(lo) | ((u32)f2bf(hi) << 16);
}
__device__ __forceinline__ u32 cvtpk(float lo, float hi) {
  u32 r;
  asm("v_cvt_pk_bf16_f32 %0, %1, %2" : "=v"(r) : "v"(lo), "v"(hi));
  return r;
}
// Raw v_exp_f32 (2^x): avoids OCML exp2f's clamp/denorm fixup sequence.
__device__ __forceinline__ float exp2a(float x) {
  float r;
  asm("v_exp_f32 %0, %1" : "=v"(r) : "v"(x));
  return r;
}
__device__ __forceinline__ float bf2f(u16 b) { return __uint_as_float((u32)b << 16); }
// Read a bf16x8 fragment from a [rows][64] bf16 LDS tile with st-style XOR swizzle.
__device__ __forceinline__ bf16x8 ldfrag(const u16* lds, int row, int kbyte) {
  return *(const bf16x8*)&lds[row * 64 + ((kbyte ^ ((row & 7) << 4)) >> 1)];
}

__global__ __launch_bounds__(256) void cvt_bf16(const float* __restrict__ s, u16* __restrict__ d,
                                                int n4) {
  int i = blockIdx.x * 256 + threadIdx.x;
  if (i < n4) {
    float4 f = ((const float4*)s)[i];
    uint2 o;
    o.x = pk2(f.x, f.y);
    o.y = pk2(f.z, f.w);
    ((uint2*)d)[i] = o;
  }
}

// Fused conversion: blocks 0..4095 convert x; blocks 4096..8191 convert {Wq,Wk,Wv,Wo}.
__global__ __launch_bounds__(256) void cvt_all(const float* __restrict__ x,
                                               const float* __restrict__ w0,
                                               const float* __restrict__ w1,
                                               const float* __restrict__ w2,
                                               const float* __restrict__ w3,
                                               u16* __restrict__ xb, u16* __restrict__ d012,
                                               u16* __restrict__ d3) {
  const int bid = blockIdx.x;
  const float* s;
  u16* d;
  int i;
  if (bid < 4096) {
    s = x;
    d = xb;
    i = bid * 256 + threadIdx.x;
  } else {
    const int y = (bid - 4096) >> 10;
    s = (y == 0) ? w0 : (y == 1) ? w1 : (y == 2) ? w2 : w3;
    d = (y == 3) ? d3 : d012 + (size_t)y * 1024 * 1024;
    i = ((bid - 4096) & 1023) * 256 + threadIdx.x;
  }
  float4 f = ((const float4*)s)[i];
  uint2 o;
  o.x = pk2(f.x, f.y);
  o.y = pk2(f.z, f.w);
  ((uint2*)d)[i] = o;
}

// C = A @ W^T.  A: bf16 [4096][1024].  Single-buffered, BM=64, XCD-clustered 1D grid.
// MODE 0: QKV fused; MODE 1: out-proj, fp32 out, with fused flash-partial combine:
//   for row-blocks whose q-tile was split (jq>=16), the A-tile at K-step kt is head kt's
//   64x64 O block = (accP[pid]+accP[pid+512])/(lP[pid]+lP[pid+512]); staged via registers.
template <int MODE, bool BBF, int BM>
__global__ __launch_bounds__(256, 5) void gemm4(const u16* __restrict__ Ab,
                                                const float* __restrict__ W0,
                                                const float* __restrict__ W1,
                                                const float* __restrict__ W2,
                                                const u16* __restrict__ Bb, u16* __restrict__ Cq,
                                                u16* __restrict__ Ck, u16* __restrict__ Cvt,
                                                float* __restrict__ Cf,
                                                const u16* __restrict__ accP,
                                                const float* __restrict__ lP) {
  constexpr int MI = BM / 32;  // frags per wave in M
  __shared__ u16 Alds[BM * 64];
  __shared__ u16 Blds[128 * 64];
  const int tid = threadIdx.x, wid = tid >> 6, lane = tid & 63;
  const int lg = lane >> 4, lr = lane & 15;
  const int wr = wid >> 1, wc = wid & 1;
  const int bid = blockIdx.x;
  const int xcd = bid & 7, slot = bid >> 3;
  int bm, bn;
  if constexpr (MODE == 0) {
    bn = xcd * 3 + (slot % 3);
    bm = slot / 3;
  } else {
    bn = xcd;
    bm = slot;
  }
  const int ng = bn * 128;

  const float* Bf = nullptr;
  const u16* Bbr = nullptr;
  if constexpr (BBF) {
    Bbr = Bb + (size_t)ng * 1024;
  } else {
    if constexpr (MODE == 0)
      Bf = (ng < 1024 ? W0 : (ng < 2048 ? W1 : W2)) + (size_t)(ng & 1023) * 1024;
    else
      Bf = W0 + (size_t)ng * 1024;
  }

  f32x4 acc[MI][4];
#pragma unroll
  for (int i = 0; i < MI; ++i)
#pragma unroll
    for (int j = 0; j < 4; ++j) acc[i][j] = {0.f, 0.f, 0.f, 0.f};

  const u16* Ag0 = Ab + (size_t)(bm * BM) * 1024;
  const int srow8 = lane >> 3, schunk = lane & 7;
  const int brow = tid >> 1, bhalf = tid & 1;
  const u32 stv0 = (u32)(wid * 8 + srow8) * 2048 + (u32)(schunk ^ srow8) * 16;
  const u32 ldsd0 = (u32)(wid * 8) * 128;

  // MODE 1 split-combine setup
  const int jq = bm & 31, bb2 = bm >> 5;
  const bool splitQ = (MODE == 1) && (jq >= 16);
  const int crow = tid >> 2;             // 0..63
  const int ccs = (tid & 3) << 4;        // col seg (u16 units)
  const u32 cswz = (u32)(crow & 7) << 4; // byte swizzle for Alds row

  for (int kt = 0; kt < 16; ++kt) {
    __syncthreads();
    if (splitQ) {
      const int pid = ((bb2 * 16 + kt) << 4) + (jq - 16);
      const u16* a0 = accP + (size_t)pid * 4096 + crow * 64 + ccs;
      const u16* a1 = a0 + (size_t)512 * 4096;
      float inv = 1.f / (lP[pid * 64 + crow] + lP[(pid + 512) * 64 + crow]);
      uint4 r0 = ((const uint4*)a0)[0], r0b = ((const uint4*)a0)[1];
      uint4 r1 = ((const uint4*)a1)[0], r1b = ((const uint4*)a1)[1];
      const u16* p0 = (const u16*)&r0;
      const u16* p0b = (const u16*)&r0b;
      const u16* p1 = (const u16*)&r1;
      const u16* p1b = (const u16*)&r1b;
      u16 ov[16];
#pragma unroll
      for (int j = 0; j < 8; ++j) ov[j] = f2bf((bf2f(p0[j]) + bf2f(p1[j])) * inv);
#pragma unroll
      for (int j = 0; j < 8; ++j) ov[8 + j] = f2bf((bf2f(p0b[j]) + bf2f(p1b[j])) * inv);
      char* arow = (char*)Alds + crow * 128;
      *(uint4*)(arow + (((u32)(ccs * 2)) ^ cswz)) = *(uint4*)&ov[0];
      *(uint4*)(arow + (((u32)(ccs * 2 + 16)) ^ cswz)) = *(uint4*)&ov[8];
    } else {
      const char* At = (const char*)Ag0 + (size_t)kt * 128;
#pragma unroll
      for (int c = 0; c < BM / 32; ++c)
        gld16(At + stv0 + c * 65536, (char*)Alds + ldsd0 + c * 4096);
    }
    if constexpr (BBF) {
      const char* Bt = (const char*)Bbr + (size_t)kt * 128;
#pragma unroll
      for (int c = 0; c < 4; ++c)
        gld16(Bt + stv0 + c * 65536, (char*)Blds + ldsd0 + c * 4096);
    } else {
      const float* s = Bf + (size_t)brow * 1024 + kt * 64 + bhalf * 32;
#pragma unroll
      for (int q = 0; q < 4; ++q) {
        float4 f0 = ((const float4*)s)[2 * q];
        float4 f1 = ((const float4*)s)[2 * q + 1];
        uint4 w;
        w.x = pk2(f0.x, f0.y);
        w.y = pk2(f0.z, f0.w);
        w.z = pk2(f1.x, f1.y);
        w.w = pk2(f1.z, f1.w);
        int ch = (bhalf * 4 + q) ^ (brow & 7);
        *(uint4*)&Blds[brow * 64 + ch * 8] = w;
      }
    }
    __syncthreads();

#pragma unroll
    for (int ks = 0; ks < 2; ++ks) {
      bf16x8 af[MI], bfr[4];
#pragma unroll
      for (int mi = 0; mi < MI; ++mi)
        af[mi] = ldfrag(Alds, wr * (BM / 2) + mi * 16 + lr, ks * 64 + lg * 16);
#pragma unroll
      for (int ni = 0; ni < 4; ++ni) bfr[ni] = ldfrag(Blds, wc * 64 + ni * 16 + lr, ks * 64 + lg * 16);
#pragma unroll
      for (int mi = 0; mi < MI; ++mi)
#pragma unroll
        for (int ni = 0; ni < 4; ++ni) acc[mi][ni] = MFMA16(af[mi], bfr[ni], acc[mi][ni]);
    }
  }

  if constexpr (MODE == 1) {
#pragma unroll
    for (int mi = 0; mi < MI; ++mi)
#pragma unroll
      for (int r = 0; r < 4; ++r) {
        int m = bm * BM + wr * (BM / 2) + mi * 16 + lg * 4 + r;
#pragma unroll
        for (int ni = 0; ni < 4; ++ni)
          Cf[(size_t)m * 1024 + ng + wc * 64 + ni * 16 + lr] = acc[mi][ni][r];
      }
  } else if (ng < 2048) {
    u16* C = (ng < 1024) ? Cq : Ck;
    const float qs = (ng < 1024) ? 0.0450842200f : 1.0f;  // (1/32)*log2(e) folded into Q
    const int nb = ng & 1023;
#pragma unroll
    for (int mi = 0; mi < MI; ++mi)
#pragma unroll
      for (int r = 0; r < 4; ++r) {
        int m = bm * BM + wr * (BM / 2) + mi * 16 + lg * 4 + r;
#pragma unroll
        for (int ni = 0; ni < 4; ++ni)
          C[(size_t)m * 1024 + nb + wc * 64 + ni * 16 + lr] = f2bf(acc[mi][ni][r] * qs);
      }
  } else {
    const int bnum = (bm * BM) >> 11;
    const int nvb = (ng - 2048) + wc * 64;
#pragma unroll
    for (int mi = 0; mi < MI; ++mi) {
      int tb = ((bm * BM) & 2047) + wr * (BM / 2) + mi * 16 + lg * 4;
#pragma unroll
      for (int ni = 0; ni < 4; ++ni) {
        int nv = nvb + ni * 16 + lr;
        ushort4 st;
        st.x = f2bf(acc[mi][ni][0]);
        st.y = f2bf(acc[mi][ni][1]);
        st.z = f2bf(acc[mi][ni][2]);
        st.w = f2bf(acc[mi][ni][3]);
        *(ushort4*)&Cvt[((size_t)(bnum << 10) + nv) * 2048 + tb] = st;
      }
    }
  }
}

// ---- Single-launch split-kv flash, hoisted addressing + raw v_exp_f32 (flashD) ----
__global__ __launch_bounds__(256, 4) void flashD(const u16* __restrict__ Qb,
                                                 const u16* __restrict__ Kb,
                                                 const u16* __restrict__ Vt,
                                                 u16* __restrict__ Ob, u16* __restrict__ accP,
                                                 float* __restrict__ lP) {
  __shared__ u16 Klds[2][64 * 64];
  __shared__ u16 Vlds[2][64 * 64];
  __shared__ u16 Plds[4][16 * 64];
  const int tid = threadIdx.x, wid = tid >> 6, lane = tid & 63;
  const int lg = lane >> 4, lr = lane & 15;
  const int bid = blockIdx.x;
  const int xcd = bid & 7;
  const int slot = bid >> 3;  // 0..191
  int g, jq;
  bool typeY;
  if (slot < 64) {
    g = slot >> 4;
    jq = 16 + (slot & 15);
    typeY = false;
  } else {
    int idx = slot - 64;
    int len = 16 - (idx >> 3);
    int j = idx & 7;
    g = j & 3;
    typeY = (j >> 2) != 0;
    jq = typeY ? (15 + len) : (len - 1);
  }
  const int hb = xcd * 4 + g;
  const int hh = hb & 15, bb = hb >> 4;
  const int q0 = jq * 64;
  const int t0 = typeY ? 16 : 0;
  const int t1 = (!typeY && jq >= 16) ? 16 : (jq + 1);
  const size_t baseqk = ((size_t)bb * 2048) * 1024 + hh * 64;
  const int srow8 = lane >> 3, schunk = lane & 7, ch = schunk ^ srow8;

  const u32 kvo0 = (u32)(wid * 8 + srow8) * 2048 + ch * 16;
  const u32 kvo1 = kvo0 + 32 * 2048;
  const u32 vvo0 = (u32)(wid * 8 + srow8) * 4096 + ch * 16;
  const u32 vvo1 = vvo0 + 32 * 4096;
  const char* Kgp = (const char*)(Kb + baseqk);
  const char* Vgp = (const char*)(Vt + ((size_t)(bb * 1024 + hh * 64)) * 2048);
  const u32 ldsr0 = (u32)(wid * 8) * 128;
  const u32 ldsr1 = ldsr0 + 4096;

  const u32 swzb = (u32)(lr & 7) << 4;
  const char* kfb0 = (const char*)Klds + lr * 128 + ((lg * 16) ^ swzb);
  const char* kfb1 = (const char*)Klds + lr * 128 + ((64 + lg * 16) ^ swzb);
  const char* vfb0 = (const char*)Vlds + lr * 128 + ((lg * 16) ^ swzb);
  const char* vfb1 = (const char*)Vlds + lr * 128 + ((64 + lg * 16) ^ swzb);
  u16* Pw = &Plds[wid][0];
  const int pswz = (lr & 7) << 3;
  const char* pr0 = (const char*)Pw + lr * 128 + (((lg * 8) ^ pswz) * 2);
  const char* pr1 = (const char*)Pw + lr * 128 + (((32 + lg * 8) ^ pswz) * 2);

  bf16x8 qf[2];
  {
    const u16* qp = Qb + baseqk + (size_t)(q0 + wid * 16 + lr) * 1024 + lg * 8;
    qf[0] = *(const bf16x8*)qp;
    qf[1] = *(const bf16x8*)(qp + 32);
  }
  f32x4 acc[4];
#pragma unroll
  for (int dt = 0; dt < 4; ++dt) acc[dt] = {0.f, 0.f, 0.f, 0.f};
  float l_r = 0.f;
  const int qrow = q0 + wid * 16 + lr;

#define STAGE(BUF, KT)                                                  \
  do {                                                                  \
    const char* Kt_ = Kgp + (size_t)(KT) * 131072;                      \
    const char* Vt_ = Vgp + (size_t)(KT) * 128;                         \
    gld16(Kt_ + kvo0, (char*)Klds + (BUF) * 8192 + ldsr0);              \
    gld16(Kt_ + kvo1, (char*)Klds + (BUF) * 8192 + ldsr1);              \
    gld16(Vt_ + vvo0, (char*)Vlds + (BUF) * 8192 + ldsr0);              \
    gld16(Vt_ + vvo1, (char*)Vlds + (BUF) * 8192 + ldsr1);              \
  } while (0)

#define FTILE(BUF, T)                                                            \
  do {                                                                           \
    const int t_ = (T);                                                          \
    if (t_ + 1 < t1) STAGE((BUF) ^ 1, t_ + 1);                                   \
    f32x4 s[4];                                                                  \
    _Pragma("unroll") for (int ni = 0; ni < 4; ++ni) s[ni] = {0.f, 0.f, 0.f, 0.f}; \
    __builtin_amdgcn_s_setprio(1);                                               \
    _Pragma("unroll") for (int ni = 0; ni < 4; ++ni) {                           \
      bf16x8 kb = *(const bf16x8*)(kfb0 + (BUF) * 8192 + ni * 2048);             \
      s[ni] = MFMA16(kb, qf[0], s[ni]);                                          \
    }                                                                            \
    _Pragma("unroll") for (int ni = 0; ni < 4; ++ni) {                           \
      bf16x8 kb = *(const bf16x8*)(kfb1 + (BUF) * 8192 + ni * 2048);             \
      s[ni] = MFMA16(kb, qf[1], s[ni]);                                          \
    }                                                                            \
    __builtin_amdgcn_s_setprio(0);                                               \
    float p[4][4];                                                               \
    float rs = 0.f;                                                              \
    const int kv0_ = t_ * 64;                                                    \
    if (t_ == jq) {                                                              \
      _Pragma("unroll") for (int ni = 0; ni < 4; ++ni)                           \
      _Pragma("unroll") for (int r = 0; r < 4; ++r) {                            \
        float v = s[ni][r];                                                      \
        if (kv0_ + ni * 16 + lg * 4 + r > qrow) v = -1e30f;                      \
        v = exp2a(v);                                                            \
        p[ni][r] = v;                                                            \
        rs += v;                                                                 \
      }                                                                          \
    } else {                                                                     \
      _Pragma("unroll") for (int ni = 0; ni < 4; ++ni)                           \
      _Pragma("unroll") for (int r = 0; r < 4; ++r) {                            \
        float v = exp2a(s[ni][r]);                                               \
        p[ni][r] = v;                                                            \
        rs += v;                                                                 \
      }                                                                          \
    }                                                                            \
    l_r += rs;                                                                   \
    _Pragma("unroll") for (int ni = 0; ni < 4; ++ni) {                           \
      _Pragma("unroll") for (int h = 0; h < 2; ++h) {                            \
        u32 w = cvtpk(p[ni][2 * h], p[ni][2 * h + 1]);                           \
        int col = (ni * 16 + lg * 4 + 2 * h) ^ pswz;                             \
        *(u32*)((char*)Pw + lr * 128 + col * 2) = w;                             \
      }                                                                          \
    }                                                                            \
    bf16x8 pb0 = *(const bf16x8*)pr0;                                            \
    bf16x8 pb1 = *(const bf16x8*)pr1;                                            \
    __builtin_amdgcn_s_setprio(1);                                               \
    _Pragma("unroll") for (int dt = 0; dt < 4; ++dt) {                           \
      bf16x8 a0 = *(const bf16x8*)(vfb0 + (BUF) * 8192 + dt * 2048);             \
      bf16x8 a1 = *(const bf16x8*)(vfb1 + (BUF) * 8192 + dt * 2048);             \
      acc[dt] = MFMA16(a0, pb0, acc[dt]);                                        \
      acc[dt] = MFMA16(a1, pb1, acc[dt]);                                        \
    }                                                                            \
    __builtin_amdgcn_s_setprio(0);                                               \
    __syncthreads();                                                             \
  } while (0)

  STAGE(0, t0);
  __syncthreads();
  int t = t0;
  for (; t + 2 <= t1; t += 2) {
    FTILE(0, t);
    FTILE(1, t + 1);
  }
  if (t < t1) FTILE(0, t);

#undef STAGE
#undef FTILE

  if (!typeY && jq < 16) {  // direct O
    l_r += __shfl_xor(l_r, 16);
    l_r += __shfl_xor(l_r, 32);
    float inv = 1.f / l_r;
    u16* orow = Ob + baseqk + (size_t)qrow * 1024 + lg * 4;
#pragma unroll
    for (int dt = 0; dt < 4; ++dt) {
      ushort4 st;
      st.x = f2bf(acc[dt][0] * inv);
      st.y = f2bf(acc[dt][1] * inv);
      st.z = f2bf(acc[dt][2] * inv);
      st.w = f2bf(acc[dt][3] * inv);
      *(ushort4*)&orow[dt * 16] = st;
    }
  } else {
    const int p = (typeY ? 512 : 0) + hb * 16 + (jq - 16);
    u16* pp = accP + (size_t)p * 4096 + (size_t)(wid * 16 + lr) * 64 + lg * 4;
#pragma unroll
    for (int dt = 0; dt < 4; ++dt) {
      ushort4 st;
      st.x = f2bf(acc[dt][0]);
      st.y = f2bf(acc[dt][1]);
      st.z = f2bf(acc[dt][2]);
      st.w = f2bf(acc[dt][3]);
      *(ushort4*)&pp[dt * 16] = st;
    }
    l_r += __shfl_xor(l_r, 16);
    l_r += __shfl_xor(l_r, 32);
    if (lg == 0) lP[p * 64 + wid * 16 + lr] = l_r;
  }
}

extern "C" void kernel_launch(void* const* d_in, const int* in_sizes, int n_in, void* d_out,
                              int out_size, void* d_ws, size_t ws_size, hipStream_t stream) {
  const float* x = (const float*)d_in[0];
  const float* Wq = (const float*)d_in[1];
  const float* Wk = (const float*)d_in[2];
  const float* Wv = (const float*)d_in[3];
  const float* Wo = (const float*)d_in[4];
  float* out = (float*)d_out;

  u16* xb = (u16*)d_ws;                 // [4096][1024] bf16 (8 MB); reused as flash partials
  u16* Qb = xb + (size_t)4096 * 1024;   // 8 MB
  u16* Kb = Qb + (size_t)4096 * 1024;   // 8 MB
  u16* Vt = Kb + (size_t)4096 * 1024;   // 8 MB (transposed V)
  u16* Ob = Qb;                         // O overwrites Q (per-block rows, safe)
  u16* Wb = Vt + (size_t)4096 * 1024;   // [3072][1024] bf16 (6 MB)  -- full path only
  u16* Wob = Wb + (size_t)3072 * 1024;  // [1024][1024] bf16 (2 MB)
  u16* accP = xb;                       // 1024 x 8KB = 8 MB (xb dead after QKV GEMM)

  const bool full = ws_size >= ((size_t)40 << 20);
  float* lP = full ? (float*)Wb : (float*)(Vt + (size_t)4096 * 1024);

  if (full) {
    cvt_all<<<8192, 256, 0, stream>>>(x, Wq, Wk, Wv, Wo, xb, Wb, Wob);
    gemm4<0, true, 64><<<1536, 256, 0, stream>>>(xb, nullptr, nullptr, nullptr, Wb, Qb, Kb, Vt,
                                                 nullptr, nullptr, nullptr);
    flashD<<<1536, 256, 0, stream>>>(Qb, Kb, Vt, Ob, accP, lP);
    gemm4<1, true, 64><<<512, 256, 0, stream>>>(Ob, nullptr, nullptr, nullptr, Wob, nullptr,
                                                nullptr, nullptr, out, accP, lP);
  } else {
    cvt_bf16<<<4096, 256, 0, stream>>>(x, xb, 4096 * 1024 / 4);
    gemm4<0, false, 64><<<1536, 256, 0, stream>>>(xb, Wq, Wk, Wv, nullptr, Qb, Kb, Vt, nullptr,
                                                  nullptr, nullptr);
    flashD<<<1536, 256, 0, stream>>>(Qb, Kb, Vt, Ob, accP, lP);
    gemm4<1, false, 64><<<512, 256, 0, stream>>>(Ob, Wo, nullptr, nullptr, nullptr, nullptr,
                                                 nullptr, nullptr, out, accP, lP);
  }
}

// Round 22
// 102.365 us; speedup vs baseline: 1.0517x; 1.0517x over previous
//
#include <hip/hip_runtime.h>
#include <hip/hip_bf16.h>

typedef __attribute__((ext_vector_type(8))) short bf16x8;
typedef __attribute__((ext_vector_type(4))) float f32x4;
typedef unsigned short u16;
typedef unsigned int u32;

#define MFMA16(a, b, c) __builtin_amdgcn_mfma_f32_16x16x32_bf16((a), (b), (c), 0, 0, 0)

__device__ __forceinline__ void gld16(const void* g, void* l) {
  __builtin_amdgcn_global_load_lds((const __attribute__((address_space(1))) u32*)g,
                                   (__attribute__((address_space(3))) u32*)l, 16, 0, 0);
}

__device__ __forceinline__ u16 f2bf(float f) {
  u32 x = __float_as_uint(f);
  x += 0x7fffu + ((x >> 16) & 1u);
  return (u16)(x >> 16);
}
__device__ __forceinline__ u32 pk2(float lo, float hi) {
  return (u32)f2bf(lo) | ((u32)f2bf(hi) << 16);
}
__device__ __forceinline__ u32 cvtpk(float lo, float hi) {
  u32 r;
  asm("v_cvt_pk_bf16_f32 %0, %1, %2" : "=v"(r) : "v"(lo), "v"(hi));
  return r;
}
// Raw v_exp_f32 (2^x): avoids OCML exp2f's clamp/denorm fixup sequence.
__device__ __forceinline__ float exp2a(float x) {
  float r;
  asm("v_exp_f32 %0, %1" : "=v"(r) : "v"(x));
  return r;
}
// Read a bf16x8 fragment from a [rows][64] bf16 LDS tile with st-style XOR swizzle.
__device__ __forceinline__ bf16x8 ldfrag(const u16* lds, int row, int kbyte) {
  return *(const bf16x8*)&lds[row * 64 + ((kbyte ^ ((row & 7) << 4)) >> 1)];
}

__global__ __launch_bounds__(256) void cvt_bf16(const float* __restrict__ s, u16* __restrict__ d,
                                                int n4) {
  int i = blockIdx.x * 256 + threadIdx.x;
  if (i < n4) {
    float4 f = ((const float4*)s)[i];
    uint2 o;
    o.x = pk2(f.x, f.y);
    o.y = pk2(f.z, f.w);
    ((uint2*)d)[i] = o;
  }
}

// Fused conversion: blocks 0..4095 convert x; blocks 4096..8191 convert {Wq,Wk,Wv,Wo}.
__global__ __launch_bounds__(256) void cvt_all(const float* __restrict__ x,
                                               const float* __restrict__ w0,
                                               const float* __restrict__ w1,
                                               const float* __restrict__ w2,
                                               const float* __restrict__ w3,
                                               u16* __restrict__ xb, u16* __restrict__ d012,
                                               u16* __restrict__ d3) {
  const int bid = blockIdx.x;
  const float* s;
  u16* d;
  int i;
  if (bid < 4096) {
    s = x;
    d = xb;
    i = bid * 256 + threadIdx.x;
  } else {
    const int y = (bid - 4096) >> 10;
    s = (y == 0) ? w0 : (y == 1) ? w1 : (y == 2) ? w2 : w3;
    d = (y == 3) ? d3 : d012 + (size_t)y * 1024 * 1024;
    i = ((bid - 4096) & 1023) * 256 + threadIdx.x;
  }
  float4 f = ((const float4*)s)[i];
  uint2 o;
  o.x = pk2(f.x, f.y);
  o.y = pk2(f.z, f.w);
  ((uint2*)d)[i] = o;
}

// C = A @ W^T.  A: bf16 [4096][1024].  Single-buffered, BM=64, XCD-clustered 1D grid.
// launch_bounds(256,5): cap VGPR at 102 so LDS (24KB -> 6 blocks/CU) is the occupancy limit.
template <int MODE, bool BBF, int BM>
__global__ __launch_bounds__(256, 5) void gemm4(const u16* __restrict__ Ab,
                                                const float* __restrict__ W0,
                                                const float* __restrict__ W1,
                                                const float* __restrict__ W2,
                                                const u16* __restrict__ Bb, u16* __restrict__ Cq,
                                                u16* __restrict__ Ck, u16* __restrict__ Cvt,
                                                float* __restrict__ Cf) {
  constexpr int MI = BM / 32;  // frags per wave in M
  __shared__ u16 Alds[BM * 64];
  __shared__ u16 Blds[128 * 64];
  const int tid = threadIdx.x, wid = tid >> 6, lane = tid & 63;
  const int lg = lane >> 4, lr = lane & 15;
  const int wr = wid >> 1, wc = wid & 1;
  const int bid = blockIdx.x;
  const int xcd = bid & 7, slot = bid >> 3;
  int bm, bn;
  if constexpr (MODE == 0) {
    bn = xcd * 3 + (slot % 3);
    bm = slot / 3;
  } else {
    bn = xcd;
    bm = slot;
  }
  const int ng = bn * 128;

  const float* Bf = nullptr;
  const u16* Bbr = nullptr;
  if constexpr (BBF) {
    Bbr = Bb + (size_t)ng * 1024;
  } else {
    if constexpr (MODE == 0)
      Bf = (ng < 1024 ? W0 : (ng < 2048 ? W1 : W2)) + (size_t)(ng & 1023) * 1024;
    else
      Bf = W0 + (size_t)ng * 1024;
  }

  f32x4 acc[MI][4];
#pragma unroll
  for (int i = 0; i < MI; ++i)
#pragma unroll
    for (int j = 0; j < 4; ++j) acc[i][j] = {0.f, 0.f, 0.f, 0.f};

  const u16* Ag0 = Ab + (size_t)(bm * BM) * 1024;
  const int srow8 = lane >> 3, schunk = lane & 7;
  const int brow = tid >> 1, bhalf = tid & 1;
  const u32 stv0 = (u32)(wid * 8 + srow8) * 2048 + (u32)(schunk ^ srow8) * 16;
  const u32 ldsd0 = (u32)(wid * 8) * 128;

  for (int kt = 0; kt < 16; ++kt) {
    __syncthreads();
    {
      const char* At = (const char*)Ag0 + (size_t)kt * 128;
#pragma unroll
      for (int c = 0; c < BM / 32; ++c)
        gld16(At + stv0 + c * 65536, (char*)Alds + ldsd0 + c * 4096);
    }
    if constexpr (BBF) {
      const char* Bt = (const char*)Bbr + (size_t)kt * 128;
#pragma unroll
      for (int c = 0; c < 4; ++c)
        gld16(Bt + stv0 + c * 65536, (char*)Blds + ldsd0 + c * 4096);
    } else {
      const float* s = Bf + (size_t)brow * 1024 + kt * 64 + bhalf * 32;
#pragma unroll
      for (int q = 0; q < 4; ++q) {
        float4 f0 = ((const float4*)s)[2 * q];
        float4 f1 = ((const float4*)s)[2 * q + 1];
        uint4 w;
        w.x = pk2(f0.x, f0.y);
        w.y = pk2(f0.z, f0.w);
        w.z = pk2(f1.x, f1.y);
        w.w = pk2(f1.z, f1.w);
        int ch = (bhalf * 4 + q) ^ (brow & 7);
        *(uint4*)&Blds[brow * 64 + ch * 8] = w;
      }
    }
    __syncthreads();

#pragma unroll
    for (int ks = 0; ks < 2; ++ks) {
      bf16x8 af[MI], bfr[4];
#pragma unroll
      for (int mi = 0; mi < MI; ++mi)
        af[mi] = ldfrag(Alds, wr * (BM / 2) + mi * 16 + lr, ks * 64 + lg * 16);
#pragma unroll
      for (int ni = 0; ni < 4; ++ni) bfr[ni] = ldfrag(Blds, wc * 64 + ni * 16 + lr, ks * 64 + lg * 16);
#pragma unroll
      for (int mi = 0; mi < MI; ++mi)
#pragma unroll
        for (int ni = 0; ni < 4; ++ni) acc[mi][ni] = MFMA16(af[mi], bfr[ni], acc[mi][ni]);
    }
  }

  if constexpr (MODE == 1) {
#pragma unroll
    for (int mi = 0; mi < MI; ++mi)
#pragma unroll
      for (int r = 0; r < 4; ++r) {
        int m = bm * BM + wr * (BM / 2) + mi * 16 + lg * 4 + r;
#pragma unroll
        for (int ni = 0; ni < 4; ++ni)
          Cf[(size_t)m * 1024 + ng + wc * 64 + ni * 16 + lr] = acc[mi][ni][r];
      }
  } else if (ng < 2048) {
    u16* C = (ng < 1024) ? Cq : Ck;
    const float qs = (ng < 1024) ? 0.0450842200f : 1.0f;  // (1/32)*log2(e) folded into Q
    const int nb = ng & 1023;
#pragma unroll
    for (int mi = 0; mi < MI; ++mi)
#pragma unroll
      for (int r = 0; r < 4; ++r) {
        int m = bm * BM + wr * (BM / 2) + mi * 16 + lg * 4 + r;
#pragma unroll
        for (int ni = 0; ni < 4; ++ni)
          C[(size_t)m * 1024 + nb + wc * 64 + ni * 16 + lr] = f2bf(acc[mi][ni][r] * qs);
      }
  } else {
    const int bnum = (bm * BM) >> 11;
    const int nvb = (ng - 2048) + wc * 64;
#pragma unroll
    for (int mi = 0; mi < MI; ++mi) {
      int tb = ((bm * BM) & 2047) + wr * (BM / 2) + mi * 16 + lg * 4;
#pragma unroll
      for (int ni = 0; ni < 4; ++ni) {
        int nv = nvb + ni * 16 + lr;
        ushort4 st;
        st.x = f2bf(acc[mi][ni][0]);
        st.y = f2bf(acc[mi][ni][1]);
        st.z = f2bf(acc[mi][ni][2]);
        st.w = f2bf(acc[mi][ni][3]);
        *(ushort4*)&Cvt[((size_t)(bnum << 10) + nv) * 2048 + tb] = st;
      }
    }
  }
}

// ---- Single-launch split-kv flash, hoisted addressing + raw v_exp_f32 ----
__global__ __launch_bounds__(256, 4) void flashD(const u16* __restrict__ Qb,
                                                 const u16* __restrict__ Kb,
                                                 const u16* __restrict__ Vt,
                                                 u16* __restrict__ Ob, u16* __restrict__ accP,
                                                 float* __restrict__ lP) {
  __shared__ u16 Klds[2][64 * 64];
  __shared__ u16 Vlds[2][64 * 64];
  __shared__ u16 Plds[4][16 * 64];
  const int tid = threadIdx.x, wid = tid >> 6, lane = tid & 63;
  const int lg = lane >> 4, lr = lane & 15;
  const int bid = blockIdx.x;
  const int xcd = bid & 7;
  const int slot = bid >> 3;  // 0..191
  int g, jq;
  bool typeY;
  if (slot < 64) {
    g = slot >> 4;
    jq = 16 + (slot & 15);
    typeY = false;
  } else {
    int idx = slot - 64;
    int len = 16 - (idx >> 3);
    int j = idx & 7;
    g = j & 3;
    typeY = (j >> 2) != 0;
    jq = typeY ? (15 + len) : (len - 1);
  }
  const int hb = xcd * 4 + g;
  const int hh = hb & 15, bb = hb >> 4;
  const int q0 = jq * 64;
  const int t0 = typeY ? 16 : 0;
  const int t1 = (!typeY && jq >= 16) ? 16 : (jq + 1);
  const size_t baseqk = ((size_t)bb * 2048) * 1024 + hh * 64;
  const int srow8 = lane >> 3, schunk = lane & 7, ch = schunk ^ srow8;

  const u32 kvo0 = (u32)(wid * 8 + srow8) * 2048 + ch * 16;
  const u32 kvo1 = kvo0 + 32 * 2048;
  const u32 vvo0 = (u32)(wid * 8 + srow8) * 4096 + ch * 16;
  const u32 vvo1 = vvo0 + 32 * 4096;
  const char* Kgp = (const char*)(Kb + baseqk);
  const char* Vgp = (const char*)(Vt + ((size_t)(bb * 1024 + hh * 64)) * 2048);
  const u32 ldsr0 = (u32)(wid * 8) * 128;
  const u32 ldsr1 = ldsr0 + 4096;

  const u32 swzb = (u32)(lr & 7) << 4;
  const char* kfb0 = (const char*)Klds + lr * 128 + ((lg * 16) ^ swzb);
  const char* kfb1 = (const char*)Klds + lr * 128 + ((64 + lg * 16) ^ swzb);
  const char* vfb0 = (const char*)Vlds + lr * 128 + ((lg * 16) ^ swzb);
  const char* vfb1 = (const char*)Vlds + lr * 128 + ((64 + lg * 16) ^ swzb);
  u16* Pw = &Plds[wid][0];
  const int pswz = (lr & 7) << 3;
  const char* pr0 = (const char*)Pw + lr * 128 + (((lg * 8) ^ pswz) * 2);
  const char* pr1 = (const char*)Pw + lr * 128 + (((32 + lg * 8) ^ pswz) * 2);

  bf16x8 qf[2];
  {
    const u16* qp = Qb + baseqk + (size_t)(q0 + wid * 16 + lr) * 1024 + lg * 8;
    qf[0] = *(const bf16x8*)qp;
    qf[1] = *(const bf16x8*)(qp + 32);
  }
  f32x4 acc[4];
#pragma unroll
  for (int dt = 0; dt < 4; ++dt) acc[dt] = {0.f, 0.f, 0.f, 0.f};
  float l_r = 0.f;
  const int qrow = q0 + wid * 16 + lr;

#define STAGE(BUF, KT)                                                  \
  do {                                                                  \
    const char* Kt_ = Kgp + (size_t)(KT) * 131072;                      \
    const char* Vt_ = Vgp + (size_t)(KT) * 128;                         \
    gld16(Kt_ + kvo0, (char*)Klds + (BUF) * 8192 + ldsr0);              \
    gld16(Kt_ + kvo1, (char*)Klds + (BUF) * 8192 + ldsr1);              \
    gld16(Vt_ + vvo0, (char*)Vlds + (BUF) * 8192 + ldsr0);              \
    gld16(Vt_ + vvo1, (char*)Vlds + (BUF) * 8192 + ldsr1);              \
  } while (0)

#define FTILE(BUF, T)                                                            \
  do {                                                                           \
    const int t_ = (T);                                                          \
    if (t_ + 1 < t1) STAGE((BUF) ^ 1, t_ + 1);                                   \
    f32x4 s[4];                                                                  \
    _Pragma("unroll") for (int ni = 0; ni < 4; ++ni) s[ni] = {0.f, 0.f, 0.f, 0.f}; \
    __builtin_amdgcn_s_setprio(1);                                               \
    _Pragma("unroll") for (int ni = 0; ni < 4; ++ni) {                           \
      bf16x8 kb = *(const bf16x8*)(kfb0 + (BUF) * 8192 + ni * 2048);             \
      s[ni] = MFMA16(kb, qf[0], s[ni]);                                          \
    }                                                                            \
    _Pragma("unroll") for (int ni = 0; ni < 4; ++ni) {                           \
      bf16x8 kb = *(const bf16x8*)(kfb1 + (BUF) * 8192 + ni * 2048);             \
      s[ni] = MFMA16(kb, qf[1], s[ni]);                                          \
    }                                                                            \
    __builtin_amdgcn_s_setprio(0);                                               \
    float p[4][4];                                                               \
    float rs = 0.f;                                                              \
    const int kv0_ = t_ * 64;                                                    \
    if (t_ == jq) {                                                              \
      _Pragma("unroll") for (int ni = 0; ni < 4; ++ni)                           \
      _Pragma("unroll") for (int r = 0; r < 4; ++r) {                            \
        float v = s[ni][r];                                                      \
        if (kv0_ + ni * 16 + lg * 4 + r > qrow) v = -1e30f;                      \
        v = exp2a(v);                                                            \
        p[ni][r] = v;                                                            \
        rs += v;                                                                 \
      }                                                                          \
    } else {                                                                     \
      _Pragma("unroll") for (int ni = 0; ni < 4; ++ni)                           \
      _Pragma("unroll") for (int r = 0; r < 4; ++r) {                            \
        float v = exp2a(s[ni][r]);                                               \
        p[ni][r] = v;                                                            \
        rs += v;                                                                 \
      }                                                                          \
    }                                                                            \
    l_r += rs;                                                                   \
    _Pragma("unroll") for (int ni = 0; ni < 4; ++ni) {                           \
      _Pragma("unroll") for (int h = 0; h < 2; ++h) {                            \
        u32 w = cvtpk(p[ni][2 * h], p[ni][2 * h + 1]);                           \
        int col = (ni * 16 + lg * 4 + 2 * h) ^ pswz;                             \
        *(u32*)((char*)Pw + lr * 128 + col * 2) = w;                             \
      }                                                                          \
    }                                                                            \
    bf16x8 pb0 = *(const bf16x8*)pr0;                                            \
    bf16x8 pb1 = *(const bf16x8*)pr1;                                            \
    __builtin_amdgcn_s_setprio(1);                                               \
    _Pragma("unroll") for (int dt = 0; dt < 4; ++dt) {                           \
      bf16x8 a0 = *(const bf16x8*)(vfb0 + (BUF) * 8192 + dt * 2048);             \
      bf16x8 a1 = *(const bf16x8*)(vfb1 + (BUF) * 8192 + dt * 2048);             \
      acc[dt] = MFMA16(a0, pb0, acc[dt]);                                        \
      acc[dt] = MFMA16(a1, pb1, acc[dt]);                                        \
    }                                                                            \
    __builtin_amdgcn_s_setprio(0);                                               \
    __syncthreads();                                                             \
  } while (0)

  STAGE(0, t0);
  __syncthreads();
  int t = t0;
  for (; t + 2 <= t1; t += 2) {
    FTILE(0, t);
    FTILE(1, t + 1);
  }
  if (t < t1) FTILE(0, t);

#undef STAGE
#undef FTILE

  if (!typeY && jq < 16) {  // direct O
    l_r += __shfl_xor(l_r, 16);
    l_r += __shfl_xor(l_r, 32);
    float inv = 1.f / l_r;
    u16* orow = Ob + baseqk + (size_t)qrow * 1024 + lg * 4;
#pragma unroll
    for (int dt = 0; dt < 4; ++dt) {
      ushort4 st;
      st.x = f2bf(acc[dt][0] * inv);
      st.y = f2bf(acc[dt][1] * inv);
      st.z = f2bf(acc[dt][2] * inv);
      st.w = f2bf(acc[dt][3] * inv);
      *(ushort4*)&orow[dt * 16] = st;
    }
  } else {
    const int p = (typeY ? 512 : 0) + hb * 16 + (jq - 16);
    u16* pp = accP + (size_t)p * 4096 + (size_t)(wid * 16 + lr) * 64 + lg * 4;
#pragma unroll
    for (int dt = 0; dt < 4; ++dt) {
      ushort4 st;
      st.x = f2bf(acc[dt][0]);
      st.y = f2bf(acc[dt][1]);
      st.z = f2bf(acc[dt][2]);
      st.w = f2bf(acc[dt][3]);
      *(ushort4*)&pp[dt * 16] = st;
    }
    l_r += __shfl_xor(l_r, 16);
    l_r += __shfl_xor(l_r, 32);
    if (lg == 0) lP[p * 64 + wid * 16 + lr] = l_r;
  }
}

// Combine: O = (acc0 + acc1) / (l0 + l1) for the 512 split q-tiles.
__global__ __launch_bounds__(256) void fcomb(const u16* __restrict__ accP,
                                             const float* __restrict__ lP,
                                             u16* __restrict__ Ob) {
  const int pid = blockIdx.x, tid = threadIdx.x;
  const int hb = pid >> 4, jq = 16 + (pid & 15);
  const int bb = hb >> 4, hh = hb & 15;
  const int row = tid >> 2, dseg = (tid & 3) << 4;
  const u16* a0 = accP + (size_t)pid * 4096 + row * 64 + dseg;
  const u16* a1 = accP + (size_t)(pid + 512) * 4096 + row * 64 + dseg;
  float inv = 1.f / (lP[pid * 64 + row] + lP[(pid + 512) * 64 + row]);
  u16 b0[16], b1[16], ov[16];
  *(uint4*)&b0[0] = ((const uint4*)a0)[0];
  *(uint4*)&b0[8] = ((const uint4*)a0)[1];
  *(uint4*)&b1[0] = ((const uint4*)a1)[0];
  *(uint4*)&b1[8] = ((const uint4*)a1)[1];
#pragma unroll
  for (int i = 0; i < 16; ++i) {
    float f = __uint_as_float((u32)b0[i] << 16) + __uint_as_float((u32)b1[i] << 16);
    ov[i] = f2bf(f * inv);
  }
  u16* od = Ob + (size_t)bb * 2048 * 1024 + (size_t)(jq * 64 + row) * 1024 + hh * 64 + dseg;
  ((uint4*)od)[0] = *(uint4*)&ov[0];
  ((uint4*)od)[1] = *(uint4*)&ov[8];
}

extern "C" void kernel_launch(void* const* d_in, const int* in_sizes, int n_in, void* d_out,
                              int out_size, void* d_ws, size_t ws_size, hipStream_t stream) {
  const float* x = (const float*)d_in[0];
  const float* Wq = (const float*)d_in[1];
  const float* Wk = (const float*)d_in[2];
  const float* Wv = (const float*)d_in[3];
  const float* Wo = (const float*)d_in[4];
  float* out = (float*)d_out;

  u16* xb = (u16*)d_ws;                 // [4096][1024] bf16 (8 MB); reused as flash partials
  u16* Qb = xb + (size_t)4096 * 1024;   // 8 MB
  u16* Kb = Qb + (size_t)4096 * 1024;   // 8 MB
  u16* Vt = Kb + (size_t)4096 * 1024;   // 8 MB (transposed V)
  u16* Ob = Qb;                         // O overwrites Q (per-block rows, safe)
  u16* Wb = Vt + (size_t)4096 * 1024;   // [3072][1024] bf16 (6 MB)  -- full path only
  u16* Wob = Wb + (size_t)3072 * 1024;  // [1024][1024] bf16 (2 MB)
  u16* accP = xb;                       // 1024 x 8KB = 8 MB (xb dead after QKV GEMM)

  const bool full = ws_size >= ((size_t)40 << 20);
  float* lP = full ? (float*)Wb : (float*)(Vt + (size_t)4096 * 1024);

  if (full) {
    cvt_all<<<8192, 256, 0, stream>>>(x, Wq, Wk, Wv, Wo, xb, Wb, Wob);
    gemm4<0, true, 64><<<1536, 256, 0, stream>>>(xb, nullptr, nullptr, nullptr, Wb, Qb, Kb, Vt,
                                                 nullptr);
    flashD<<<1536, 256, 0, stream>>>(Qb, Kb, Vt, Ob, accP, lP);
    fcomb<<<512, 256, 0, stream>>>(accP, lP, Ob);
    gemm4<1, true, 64><<<512, 256, 0, stream>>>(Ob, nullptr, nullptr, nullptr, Wob, nullptr,
                                                nullptr, nullptr, out);
  } else {
    cvt_bf16<<<4096, 256, 0, stream>>>(x, xb, 4096 * 1024 / 4);
    gemm4<0, false, 64><<<1536, 256, 0, stream>>>(xb, Wq, Wk, Wv, nullptr, Qb, Kb, Vt, nullptr);
    flashD<<<1536, 256, 0, stream>>>(Qb, Kb, Vt, Ob, accP, lP);
    fcomb<<<512, 256, 0, stream>>>(accP, lP, Ob);
    gemm4<1, false, 64><<<512, 256, 0, stream>>>(Ob, Wo, nullptr, nullptr, nullptr, nullptr,
                                                 nullptr, nullptr, out);
  }
}